// Round 13
// baseline (110.047 us; speedup 1.0000x reference)
//
#include <hip/hip_runtime.h>
#include <hip/hip_fp16.h>

// Node record: 16 halves = 32B
//   [0..8] Frame (row-major)  [9..11] pF = pos@Frame  [12..14] pos  [15] sA
#define RSTRIDE 16

#define KPB 8192       // keys per bin (low 13 mantissa bits of ex hold fi&8191)
#define KPB_SHIFT 13
#define EPB 512        // edges per block chunk
#define MAXBINS 64
#define SLICES 16      // binsum parallel slices per bin
#define GSPAN 256      // max chunks per binsum block (ceil(nblk/SLICES) <= 256 for nblk<=4096)

#define SEG_PAD 16     // fallback path
#define NREP 2

__device__ __forceinline__ float silu_f(float x)
{
    return x * __builtin_amdgcn_rcpf(1.f + __expf(-x));
}

__device__ __forceinline__ void pre_one(const float* __restrict__ vec, const float* __restrict__ frame,
                                        const float* __restrict__ pos, const float* __restrict__ W,
                                        const float* __restrict__ Wa, int waOff,
                                        __half* __restrict__ out, int n, int i)
{
    if (i >= n) return;
    float w[16][3];
#pragma unroll
    for (int d = 0; d < 16; ++d) {
        w[d][0] = W[d * 3 + 0]; w[d][1] = W[d * 3 + 1]; w[d][2] = W[d * 3 + 2];
    }
    float vv[48];
    const float4* vp4 = (const float4*)(vec + (size_t)i * 48);
#pragma unroll
    for (int q = 0; q < 12; ++q) ((float4*)vv)[q] = vp4[q];

    float vt[3][3] = {{0.f}};
#pragma unroll
    for (int d = 0; d < 16; ++d) {
        float r0 = vv[d * 3 + 0], r1 = vv[d * 3 + 1], r2 = vv[d * 3 + 2];
#pragma unroll
        for (int h = 0; h < 3; ++h) {
            vt[0][h] += r0 * w[d][h];
            vt[1][h] += r1 * w[d][h];
            vt[2][h] += r2 * w[d][h];
        }
    }
    float F[9];
#pragma unroll
    for (int j = 0; j < 9; ++j) F[j] = frame[(size_t)i * 9 + j];
    float p0 = pos[(size_t)i * 3 + 0];
    float p1 = pos[(size_t)i * 3 + 1];
    float p2 = pos[(size_t)i * 3 + 2];

    float sA = 0.f;
#pragma unroll
    for (int h = 0; h < 3; ++h)
#pragma unroll
        for (int j = 0; j < 3; ++j) {
            float a = vt[0][h] * F[0 + j] + vt[1][h] * F[3 + j] + vt[2][h] * F[6 + j];
            sA += silu_f(a) * Wa[waOff + h * 3 + j];
        }

    float4 buf[2];
    __half* o = (__half*)buf;
#pragma unroll
    for (int j = 0; j < 9; ++j) o[j] = __float2half_rn(F[j]);
    o[9]  = __float2half_rn(p0 * F[0] + p1 * F[3] + p2 * F[6]);
    o[10] = __float2half_rn(p0 * F[1] + p1 * F[4] + p2 * F[7]);
    o[11] = __float2half_rn(p0 * F[2] + p1 * F[5] + p2 * F[8]);
    o[12] = __float2half_rn(p0); o[13] = __float2half_rn(p1); o[14] = __float2half_rn(p2);
    o[15] = __float2half_rn(sA);

    float4* op = (float4*)(out + (size_t)i * RSTRIDE);
    op[0] = buf[0]; op[1] = buf[1];
}

__global__ void setup_kernel(const float* __restrict__ from_vec, const float* __restrict__ from_frame,
                             const float* __restrict__ from_pos, const float* __restrict__ W_from,
                             const float* __restrict__ to_vec, const float* __restrict__ to_frame,
                             const float* __restrict__ to_pos, const float* __restrict__ W_to,
                             const float* __restrict__ Wa,
                             __half* __restrict__ fromRec, __half* __restrict__ toRec,
                             int NF, int NT, int nPreF)
{
    int b = blockIdx.x;
    if (b < nPreF)
        pre_one(from_vec, from_frame, from_pos, W_from, Wa, 0, fromRec, NF, b * 256 + (int)threadIdx.x);
    else
        pre_one(to_vec, to_frame, to_pos, W_to, Wa, 12, toRec, NT, (b - nPreF) * 256 + (int)threadIdx.x);
}

__device__ __forceinline__ unsigned wave_incl_scan(unsigned v, int lane)
{
    int x = (int)v;
#pragma unroll
    for (int d = 1; d < 64; d <<= 1) {
        int t = __shfl_up(x, d, 64);
        if (lane >= d) x += t;
    }
    return (unsigned)x;
}

// fused: compute ex, write out[e]; block-private bin-grouped scatter staged in LDS,
// written out coalesced; per-block bin offsets to binoff.
__global__ void edge_score_fused(const int* __restrict__ inc,
                                 const __half* __restrict__ fromRec, const __half* __restrict__ toRec,
                                 const float* __restrict__ Wa,
                                 unsigned* __restrict__ binoff,   // [nblk][nbins+1]
                                 float* __restrict__ ex_out, unsigned* __restrict__ pairs,
                                 int E, int nbins, int nblk)
{
    __shared__ unsigned cnt[MAXBINS + 1];
    __shared__ unsigned cur[MAXBINS];
    __shared__ unsigned stage[EPB];

    int tid = (int)threadIdx.x;
    int base = blockIdx.x * EPB;

    if (tid < MAXBINS + 1) cnt[tid] = 0;

    int e[2]; bool valid[2]; int fi[2], ti[2];
#pragma unroll
    for (int k = 0; k < 2; ++k) {
        e[k] = base + k * 256 + tid;
        valid[k] = e[k] < E;
    }
#pragma unroll
    for (int k = 0; k < 2; ++k) {
        fi[k] = valid[k] ? __builtin_nontemporal_load(inc + e[k]) : 0;
        ti[k] = valid[k] ? __builtin_nontemporal_load(inc + E + e[k]) : 0;
    }
    __syncthreads();
#pragma unroll
    for (int k = 0; k < 2; ++k)
        if (valid[k]) atomicAdd(&cnt[fi[k] >> KPB_SHIFT], 1u);
    __syncthreads();
    if (tid < 64) {
        unsigned v = (tid < nbins) ? cnt[tid] : 0u;
        unsigned incl = wave_incl_scan(v, tid);
        if (tid < nbins) { cnt[tid] = incl - v; cur[tid] = incl - v; }
        if (tid == nbins - 1) cnt[nbins] = incl;
    }
    __syncthreads();

    float wa9 = Wa[9], wa10 = Wa[10], wa11 = Wa[11];
    float wa21 = Wa[21], wa22 = Wa[22], wa23 = Wa[23];

    // issue all 4 record gathers before compute (MLP)
    float4 fb[2][2], tb[2][2];
#pragma unroll
    for (int k = 0; k < 2; ++k) {
        const float4* fp4 = (const float4*)(fromRec + (size_t)fi[k] * RSTRIDE);
        const float4* tp4 = (const float4*)(toRec + (size_t)ti[k] * RSTRIDE);
        fb[k][0] = fp4[0]; fb[k][1] = fp4[1];
        tb[k][0] = tp4[0]; tb[k][1] = tp4[1];
    }

#pragma unroll
    for (int k = 0; k < 2; ++k) {
        if (!valid[k]) continue;
        const __half* fh = (const __half*)&fb[k][0];
        const __half* th = (const __half*)&tb[k][0];
        float fr[16], tr[16];
#pragma unroll
        for (int j = 0; j < 16; ++j) fr[j] = __half2float(fh[j]);
#pragma unroll
        for (int j = 0; j < 16; ++j) tr[j] = __half2float(th[j]);

        float raw = fr[15] + tr[15];
#pragma unroll
        for (int j = 0; j < 3; ++j) {
            float fd = tr[12] * fr[j] + tr[13] * fr[3 + j] + tr[14] * fr[6 + j] - fr[9 + j];
            float td = fr[12] * tr[j] + fr[13] * tr[3 + j] + fr[14] * tr[6 + j] - tr[9 + j];
            float waf = (j == 0) ? wa9 : (j == 1) ? wa10 : wa11;
            float wat = (j == 0) ? wa21 : (j == 1) ? wa22 : wa23;
            raw += silu_f(fd) * waf + silu_f(td) * wat;
        }

        float ex = __expf(raw);  // shift-invariant softmax, |raw| << 80
        __builtin_nontemporal_store(ex, ex_out + e[k]);

        unsigned slot = atomicAdd(&cur[fi[k] >> KPB_SHIFT], 1u);
        stage[slot] = (__float_as_uint(ex) & ~(unsigned)(KPB - 1)) | (unsigned)(fi[k] & (KPB - 1));
    }
    __syncthreads();

    unsigned total = cnt[nbins];
    for (unsigned t = (unsigned)tid; t < total; t += 256)
        __builtin_nontemporal_store(stage[t], pairs + (size_t)base + t);
    if (tid <= nbins)
        binoff[(size_t)blockIdx.x * (nbins + 1) + tid] = cnt[tid];
}

// stage 1: block (b,s) sums bin b over contiguous chunk range; binoff staged in LDS
__global__ void binsum_part(const unsigned* __restrict__ pairs,
                            const unsigned* __restrict__ binoff,
                            float* __restrict__ partial, int nbins, int nblk)
{
    __shared__ float acc[KPB];
    __shared__ unsigned offs[GSPAN];
    __shared__ unsigned ends[GSPAN];
    int b = blockIdx.x / SLICES;
    int s = blockIdx.x % SLICES;
    int span = (nblk + SLICES - 1) / SLICES;
    int g0 = s * span;
    int g1 = min(nblk, g0 + span);
    int ng = g1 - g0;

#pragma unroll 8
    for (int t = threadIdx.x; t < KPB; t += 256) acc[t] = 0.f;
    for (int t = threadIdx.x; t < ng; t += 256) {
        offs[t] = binoff[(size_t)(g0 + t) * (nbins + 1) + b];
        ends[t] = binoff[(size_t)(g0 + t) * (nbins + 1) + b + 1];
    }
    __syncthreads();

    int wv = (int)(threadIdx.x >> 6);
    int lane = (int)(threadIdx.x & 63);
    for (int g = wv; g < ng; g += 4) {
        unsigned off = offs[g], end = ends[g];
        const unsigned* src = pairs + (size_t)(g0 + g) * EPB;
        for (unsigned r = off + (unsigned)lane; r < end; r += 64) {
            unsigned w = src[r];
            atomicAdd(&acc[w & (KPB - 1)], __uint_as_float(w & ~(unsigned)(KPB - 1)));
        }
    }
    __syncthreads();
    float* dst = partial + (size_t)blockIdx.x * KPB;
#pragma unroll 8
    for (int t = threadIdx.x; t < KPB; t += 256) dst[t] = acc[t];
}

// stage 2: segsum[k] = sum over slices
__global__ void binsum_reduce(const float* __restrict__ partial, float* __restrict__ segsum, int NF)
{
    int k = blockIdx.x * blockDim.x + threadIdx.x;
    if (k >= NF) return;
    int b = k >> KPB_SHIFT;
    int off = k & (KPB - 1);
    float sum = 0.f;
#pragma unroll
    for (int s = 0; s < SLICES; ++s)
        sum += partial[((size_t)b * SLICES + s) * KPB + off];
    segsum[k] = sum;
}

__global__ void edge_norm4(const int* __restrict__ inc, const float* __restrict__ segsum,
                           float* __restrict__ out, int E)
{
    int e0 = (blockIdx.x * blockDim.x + threadIdx.x) * 4;
    if (e0 + 3 < E) {
        int4 f4 = *(const int4*)(inc + e0);
        float4 x4 = *(const float4*)(out + e0);
        __builtin_nontemporal_store(x4.x * __builtin_amdgcn_rcpf(segsum[f4.x]), out + e0 + 0);
        __builtin_nontemporal_store(x4.y * __builtin_amdgcn_rcpf(segsum[f4.y]), out + e0 + 1);
        __builtin_nontemporal_store(x4.z * __builtin_amdgcn_rcpf(segsum[f4.z]), out + e0 + 2);
        __builtin_nontemporal_store(x4.w * __builtin_amdgcn_rcpf(segsum[f4.w]), out + e0 + 3);
    } else {
        for (int e = e0; e < E; ++e)
            out[e] = out[e] * __builtin_amdgcn_rcpf(segsum[inc[e]]);
    }
}

// -------- fallback: padded-replicated atomic edge_score (fp16 records) ----------
__global__ void pre_node_k(const float* __restrict__ vec, const float* __restrict__ frame,
                           const float* __restrict__ pos, const float* __restrict__ W,
                           const float* __restrict__ Wa, int waOff,
                           __half* __restrict__ out, int n)
{
    pre_one(vec, frame, pos, W, Wa, waOff, out, n, blockIdx.x * blockDim.x + (int)threadIdx.x);
}

__global__ void edge_score_pad(const int* __restrict__ inc,
                               const __half* __restrict__ fromRec, const __half* __restrict__ toRec,
                               const float* __restrict__ Wa,
                               float* __restrict__ ex_out, float* __restrict__ segsumP, int E)
{
    int e = blockIdx.x * blockDim.x + threadIdx.x;
    if (e >= E) return;
    int fi = __builtin_nontemporal_load(inc + e);
    int ti = __builtin_nontemporal_load(inc + E + e);
    float4 fbuf[2], tbuf[2];
    const float4* fp4 = (const float4*)(fromRec + (size_t)fi * RSTRIDE);
    const float4* tp4 = (const float4*)(toRec + (size_t)ti * RSTRIDE);
    fbuf[0] = fp4[0]; fbuf[1] = fp4[1];
    tbuf[0] = tp4[0]; tbuf[1] = tp4[1];
    const __half* fh = (const __half*)fbuf;
    const __half* th = (const __half*)tbuf;
    float fr[16], tr[16];
#pragma unroll
    for (int j = 0; j < 16; ++j) fr[j] = __half2float(fh[j]);
#pragma unroll
    for (int j = 0; j < 16; ++j) tr[j] = __half2float(th[j]);
    float raw = fr[15] + tr[15];
#pragma unroll
    for (int j = 0; j < 3; ++j) {
        float fd = tr[12] * fr[j] + tr[13] * fr[3 + j] + tr[14] * fr[6 + j] - fr[9 + j];
        float td = fr[12] * tr[j] + fr[13] * tr[3 + j] + fr[14] * tr[6 + j] - tr[9 + j];
        raw += silu_f(fd) * Wa[9 + j] + silu_f(td) * Wa[21 + j];
    }
    float ex = __expf(raw);
    __builtin_nontemporal_store(ex, ex_out + e);
    size_t slot = ((size_t)fi * NREP + (threadIdx.x & (NREP - 1))) * SEG_PAD;
    atomicAdd(&segsumP[slot], ex);
}

__global__ void seg_reduce(const float* __restrict__ segsumP, float* __restrict__ segsum, int NF)
{
    int k = blockIdx.x * blockDim.x + threadIdx.x;
    if (k >= NF) return;
    float s = 0.f;
#pragma unroll
    for (int r = 0; r < NREP; ++r) s += segsumP[((size_t)k * NREP + r) * SEG_PAD];
    segsum[k] = s;
}

extern "C" void kernel_launch(void* const* d_in, const int* in_sizes, int n_in,
                              void* d_out, int out_size, void* d_ws, size_t ws_size,
                              hipStream_t stream)
{
    const float* from_vec   = (const float*)d_in[0];
    const float* to_vec     = (const float*)d_in[1];
    const float* from_frame = (const float*)d_in[2];
    const float* to_frame   = (const float*)d_in[3];
    const float* from_pos   = (const float*)d_in[4];
    const float* to_pos     = (const float*)d_in[5];
    const float* W_from     = (const float*)d_in[6];
    const float* W_to       = (const float*)d_in[7];
    const float* W_attn     = (const float*)d_in[8];
    const int*   inc        = (const int*)d_in[9];

    const int NF = in_sizes[0] / 48;   // 50000
    const int NT = in_sizes[1] / 48;   // 100000
    const int E  = in_sizes[9] / 2;    // 1600000

    float* out = (float*)d_out;
    unsigned char* ws = (unsigned char*)d_ws;

    const int nbins = (NF + KPB - 1) >> KPB_SHIFT;        // 7
    const int nblk  = (E + EPB - 1) / EPB;                // 3125
    const int nPreF = (NF + 255) / 256;
    const int nPreT = (NT + 255) / 256;

    auto align256 = [](size_t x) { return (x + 255) & ~(size_t)255; };

    size_t offFrom = 0;                                              // partial overlays recs
    size_t offTo   = align256(offFrom + (size_t)NF * RSTRIDE * 2);   // fp16
    size_t recEnd  = offTo + (size_t)NT * RSTRIDE * 2;
    size_t offPair = align256(recEnd);
    size_t offBO   = align256(offPair + (size_t)nblk * EPB * 4);
    size_t offSeg  = align256(offBO + (size_t)nblk * (nbins + 1) * 4);
    size_t needFull = offSeg + (size_t)NF * 4;

    const size_t partialSz = (size_t)nbins * SLICES * KPB * 4;       // 3.67MB, overlays recs (4.8MB)
    const size_t recsz   = ((size_t)NF + NT) * RSTRIDE * 2;
    const size_t padsz   = (size_t)NF * NREP * SEG_PAD * 4;
    const size_t needPad = recsz + padsz + (size_t)NF * 4 + 512;

    const int B = 256;
    const int span = (nblk + SLICES - 1) / SLICES;
    if (ws_size >= needFull && nbins <= MAXBINS && partialSz <= recsz && span <= GSPAN) {
        __half*   fromRec  = (__half*)(ws + offFrom);
        __half*   toRec    = (__half*)(ws + offTo);
        unsigned* pairs    = (unsigned*)(ws + offPair);
        unsigned* binoff   = (unsigned*)(ws + offBO);
        float*    segsum   = (float*)(ws + offSeg);
        float*    partial  = (float*)(ws + offFrom);   // overlays recs (dead after fused)

        setup_kernel<<<nPreF + nPreT, B, 0, stream>>>(
            from_vec, from_frame, from_pos, W_from,
            to_vec, to_frame, to_pos, W_to, W_attn,
            fromRec, toRec, NF, NT, nPreF);
        edge_score_fused<<<nblk, B, 0, stream>>>(inc, fromRec, toRec, W_attn, binoff,
                                                 out, pairs, E, nbins, nblk);
        binsum_part<<<nbins * SLICES, B, 0, stream>>>(pairs, binoff, partial, nbins, nblk);
        binsum_reduce<<<(NF + B - 1) / B, B, 0, stream>>>(partial, segsum, NF);
        edge_norm4<<<(E / 4 + B - 1) / B, B, 0, stream>>>(inc, segsum, out, E);
    } else if (ws_size >= needPad) {
        __half* fromRec = (__half*)ws;
        __half* toRec   = fromRec + (size_t)NF * RSTRIDE;
        float* segsumP  = (float*)(ws + align256(recsz));
        float* segsum   = segsumP + (size_t)NF * NREP * SEG_PAD;
        hipMemsetAsync(segsumP, 0, padsz, stream);
        pre_node_k<<<nPreF, B, 0, stream>>>(from_vec, from_frame, from_pos, W_from, W_attn, 0,  fromRec, NF);
        pre_node_k<<<nPreT, B, 0, stream>>>(to_vec, to_frame, to_pos, W_to, W_attn, 12, toRec, NT);
        edge_score_pad<<<(E + B - 1) / B, B, 0, stream>>>(inc, fromRec, toRec, W_attn, out, segsumP, E);
        seg_reduce<<<(NF + B - 1) / B, B, 0, stream>>>(segsumP, segsum, NF);
        edge_norm4<<<(E / 4 + B - 1) / B, B, 0, stream>>>(inc, segsum, out, E);
    }
}

// Round 14
// 82.005 us; speedup vs baseline: 1.3420x; 1.3420x over previous
//
#include <hip/hip_runtime.h>
#include <hip/hip_fp16.h>

// Node record: 16 halves = 32B
//   [0..8] Frame (row-major)  [9..11] pF = pos@Frame  [12..14] pos  [15] sA
#define RSTRIDE 16

#define KPB 2048       // keys per bin (low 11 mantissa bits of ex hold fi&2047)
#define KPB_SHIFT 11
#define EPB 512        // edges per block chunk
#define MAXBINS 64
#define SLICES 23      // binsum parallel slices per bin (grid = nbins*SLICES = 575)
#define GSPAN 256      // max chunks per binsum slice (ceil(3125/23)=136)

#define SEG_PAD 16     // fallback path
#define NREP 2

__device__ __forceinline__ float silu_f(float x)
{
    return x * __builtin_amdgcn_rcpf(1.f + __expf(-x));
}

__device__ __forceinline__ void pre_one(const float* __restrict__ vec, const float* __restrict__ frame,
                                        const float* __restrict__ pos, const float* __restrict__ W,
                                        const float* __restrict__ Wa, int waOff,
                                        __half* __restrict__ out, int n, int i)
{
    if (i >= n) return;
    float w[16][3];
#pragma unroll
    for (int d = 0; d < 16; ++d) {
        w[d][0] = W[d * 3 + 0]; w[d][1] = W[d * 3 + 1]; w[d][2] = W[d * 3 + 2];
    }
    float vv[48];
    const float4* vp4 = (const float4*)(vec + (size_t)i * 48);
#pragma unroll
    for (int q = 0; q < 12; ++q) ((float4*)vv)[q] = vp4[q];

    float vt[3][3] = {{0.f}};
#pragma unroll
    for (int d = 0; d < 16; ++d) {
        float r0 = vv[d * 3 + 0], r1 = vv[d * 3 + 1], r2 = vv[d * 3 + 2];
#pragma unroll
        for (int h = 0; h < 3; ++h) {
            vt[0][h] += r0 * w[d][h];
            vt[1][h] += r1 * w[d][h];
            vt[2][h] += r2 * w[d][h];
        }
    }
    float F[9];
#pragma unroll
    for (int j = 0; j < 9; ++j) F[j] = frame[(size_t)i * 9 + j];
    float p0 = pos[(size_t)i * 3 + 0];
    float p1 = pos[(size_t)i * 3 + 1];
    float p2 = pos[(size_t)i * 3 + 2];

    float sA = 0.f;
#pragma unroll
    for (int h = 0; h < 3; ++h)
#pragma unroll
        for (int j = 0; j < 3; ++j) {
            float a = vt[0][h] * F[0 + j] + vt[1][h] * F[3 + j] + vt[2][h] * F[6 + j];
            sA += silu_f(a) * Wa[waOff + h * 3 + j];
        }

    float4 buf[2];
    __half* o = (__half*)buf;
#pragma unroll
    for (int j = 0; j < 9; ++j) o[j] = __float2half_rn(F[j]);
    o[9]  = __float2half_rn(p0 * F[0] + p1 * F[3] + p2 * F[6]);
    o[10] = __float2half_rn(p0 * F[1] + p1 * F[4] + p2 * F[7]);
    o[11] = __float2half_rn(p0 * F[2] + p1 * F[5] + p2 * F[8]);
    o[12] = __float2half_rn(p0); o[13] = __float2half_rn(p1); o[14] = __float2half_rn(p2);
    o[15] = __float2half_rn(sA);

    float4* op = (float4*)(out + (size_t)i * RSTRIDE);
    op[0] = buf[0]; op[1] = buf[1];
}

__global__ void setup_kernel(const float* __restrict__ from_vec, const float* __restrict__ from_frame,
                             const float* __restrict__ from_pos, const float* __restrict__ W_from,
                             const float* __restrict__ to_vec, const float* __restrict__ to_frame,
                             const float* __restrict__ to_pos, const float* __restrict__ W_to,
                             const float* __restrict__ Wa,
                             __half* __restrict__ fromRec, __half* __restrict__ toRec,
                             int NF, int NT, int nPreF)
{
    int b = blockIdx.x;
    if (b < nPreF)
        pre_one(from_vec, from_frame, from_pos, W_from, Wa, 0, fromRec, NF, b * 256 + (int)threadIdx.x);
    else
        pre_one(to_vec, to_frame, to_pos, W_to, Wa, 12, toRec, NT, (b - nPreF) * 256 + (int)threadIdx.x);
}

__device__ __forceinline__ unsigned wave_incl_scan(unsigned v, int lane)
{
    int x = (int)v;
#pragma unroll
    for (int d = 1; d < 64; d <<= 1) {
        int t = __shfl_up(x, d, 64);
        if (lane >= d) x += t;
    }
    return (unsigned)x;
}

// fused: compute ex, write out[e]; block-private bin-grouped scatter staged in LDS,
// written out coalesced; per-block bin offsets to binoff.
__global__ void edge_score_fused(const int* __restrict__ inc,
                                 const __half* __restrict__ fromRec, const __half* __restrict__ toRec,
                                 const float* __restrict__ Wa,
                                 unsigned* __restrict__ binoff,   // [nblk][nbins+1]
                                 float* __restrict__ ex_out, unsigned* __restrict__ pairs,
                                 int E, int nbins, int nblk)
{
    __shared__ unsigned cnt[MAXBINS + 1];
    __shared__ unsigned cur[MAXBINS];
    __shared__ unsigned stage[EPB];

    int tid = (int)threadIdx.x;
    int base = blockIdx.x * EPB;

    if (tid < MAXBINS + 1) cnt[tid] = 0;

    int e[2]; bool valid[2]; int fi[2], ti[2];
#pragma unroll
    for (int k = 0; k < 2; ++k) {
        e[k] = base + k * 256 + tid;
        valid[k] = e[k] < E;
    }
#pragma unroll
    for (int k = 0; k < 2; ++k) {
        fi[k] = valid[k] ? __builtin_nontemporal_load(inc + e[k]) : 0;
        ti[k] = valid[k] ? __builtin_nontemporal_load(inc + E + e[k]) : 0;
    }
    __syncthreads();
#pragma unroll
    for (int k = 0; k < 2; ++k)
        if (valid[k]) atomicAdd(&cnt[fi[k] >> KPB_SHIFT], 1u);
    __syncthreads();
    if (tid < 64) {
        unsigned v = (tid < nbins) ? cnt[tid] : 0u;
        unsigned incl = wave_incl_scan(v, tid);
        if (tid < nbins) { cnt[tid] = incl - v; cur[tid] = incl - v; }
        if (tid == nbins - 1) cnt[nbins] = incl;
    }
    __syncthreads();

    float wa9 = Wa[9], wa10 = Wa[10], wa11 = Wa[11];
    float wa21 = Wa[21], wa22 = Wa[22], wa23 = Wa[23];

    // issue all 4 record gathers before compute (MLP)
    float4 fb[2][2], tb[2][2];
#pragma unroll
    for (int k = 0; k < 2; ++k) {
        const float4* fp4 = (const float4*)(fromRec + (size_t)fi[k] * RSTRIDE);
        const float4* tp4 = (const float4*)(toRec + (size_t)ti[k] * RSTRIDE);
        fb[k][0] = fp4[0]; fb[k][1] = fp4[1];
        tb[k][0] = tp4[0]; tb[k][1] = tp4[1];
    }

#pragma unroll
    for (int k = 0; k < 2; ++k) {
        if (!valid[k]) continue;
        const __half* fh = (const __half*)&fb[k][0];
        const __half* th = (const __half*)&tb[k][0];
        float fr[16], tr[16];
#pragma unroll
        for (int j = 0; j < 16; ++j) fr[j] = __half2float(fh[j]);
#pragma unroll
        for (int j = 0; j < 16; ++j) tr[j] = __half2float(th[j]);

        float raw = fr[15] + tr[15];
#pragma unroll
        for (int j = 0; j < 3; ++j) {
            float fd = tr[12] * fr[j] + tr[13] * fr[3 + j] + tr[14] * fr[6 + j] - fr[9 + j];
            float td = fr[12] * tr[j] + fr[13] * tr[3 + j] + fr[14] * tr[6 + j] - tr[9 + j];
            float waf = (j == 0) ? wa9 : (j == 1) ? wa10 : wa11;
            float wat = (j == 0) ? wa21 : (j == 1) ? wa22 : wa23;
            raw += silu_f(fd) * waf + silu_f(td) * wat;
        }

        float ex = __expf(raw);  // shift-invariant softmax, |raw| << 80
        __builtin_nontemporal_store(ex, ex_out + e[k]);

        unsigned slot = atomicAdd(&cur[fi[k] >> KPB_SHIFT], 1u);
        stage[slot] = (__float_as_uint(ex) & ~(unsigned)(KPB - 1)) | (unsigned)(fi[k] & (KPB - 1));
    }
    __syncthreads();

    unsigned total = cnt[nbins];
    for (unsigned t = (unsigned)tid; t < total; t += 256)
        __builtin_nontemporal_store(stage[t], pairs + (size_t)base + t);
    if (tid <= nbins)
        binoff[(size_t)blockIdx.x * (nbins + 1) + tid] = cnt[tid];
}

// stage 1: block (b,s) sums bin b over a contiguous chunk range; 8 waves, binoff in LDS
__global__ void binsum_part(const unsigned* __restrict__ pairs,
                            const unsigned* __restrict__ binoff,
                            float* __restrict__ partial, int nbins, int nblk)
{
    __shared__ float acc[KPB];
    __shared__ unsigned offs[GSPAN];
    __shared__ unsigned ends[GSPAN];
    int b = blockIdx.x / SLICES;
    int s = blockIdx.x % SLICES;
    int span = (nblk + SLICES - 1) / SLICES;
    int g0 = s * span;
    int g1 = min(nblk, g0 + span);
    int ng = g1 - g0;

    for (int t = threadIdx.x; t < KPB; t += 512) acc[t] = 0.f;
    for (int t = threadIdx.x; t < ng; t += 512) {
        offs[t] = binoff[(size_t)(g0 + t) * (nbins + 1) + b];
        ends[t] = binoff[(size_t)(g0 + t) * (nbins + 1) + b + 1];
    }
    __syncthreads();

    int wv = (int)(threadIdx.x >> 6);      // 8 waves
    int lane = (int)(threadIdx.x & 63);
    for (int g = wv; g < ng; g += 8) {
        unsigned off = offs[g], end = ends[g];
        const unsigned* src = pairs + (size_t)(g0 + g) * EPB;
        for (unsigned r = off + (unsigned)lane; r < end; r += 64) {
            unsigned w = src[r];
            atomicAdd(&acc[w & (KPB - 1)], __uint_as_float(w & ~(unsigned)(KPB - 1)));
        }
    }
    __syncthreads();
    float* dst = partial + (size_t)blockIdx.x * KPB;
    for (int t = threadIdx.x; t < KPB; t += 512) dst[t] = acc[t];
}

// stage 2: segsum[k] = sum over slices
__global__ void binsum_reduce(const float* __restrict__ partial, float* __restrict__ segsum, int NF)
{
    int k = blockIdx.x * blockDim.x + threadIdx.x;
    if (k >= NF) return;
    int b = k >> KPB_SHIFT;
    int off = k & (KPB - 1);
    float sum = 0.f;
#pragma unroll
    for (int s = 0; s < SLICES; ++s)
        sum += partial[((size_t)b * SLICES + s) * KPB + off];
    segsum[k] = sum;
}

__global__ void edge_norm4(const int* __restrict__ inc, const float* __restrict__ segsum,
                           float* __restrict__ out, int E)
{
    int e0 = (blockIdx.x * blockDim.x + threadIdx.x) * 4;
    if (e0 + 3 < E) {
        int4 f4 = *(const int4*)(inc + e0);
        float4 x4 = *(const float4*)(out + e0);
        __builtin_nontemporal_store(x4.x * __builtin_amdgcn_rcpf(segsum[f4.x]), out + e0 + 0);
        __builtin_nontemporal_store(x4.y * __builtin_amdgcn_rcpf(segsum[f4.y]), out + e0 + 1);
        __builtin_nontemporal_store(x4.z * __builtin_amdgcn_rcpf(segsum[f4.z]), out + e0 + 2);
        __builtin_nontemporal_store(x4.w * __builtin_amdgcn_rcpf(segsum[f4.w]), out + e0 + 3);
    } else {
        for (int e = e0; e < E; ++e)
            out[e] = out[e] * __builtin_amdgcn_rcpf(segsum[inc[e]]);
    }
}

// -------- fallback: padded-replicated atomic edge_score (fp16 records) ----------
__global__ void pre_node_k(const float* __restrict__ vec, const float* __restrict__ frame,
                           const float* __restrict__ pos, const float* __restrict__ W,
                           const float* __restrict__ Wa, int waOff,
                           __half* __restrict__ out, int n)
{
    pre_one(vec, frame, pos, W, Wa, waOff, out, n, blockIdx.x * blockDim.x + (int)threadIdx.x);
}

__global__ void edge_score_pad(const int* __restrict__ inc,
                               const __half* __restrict__ fromRec, const __half* __restrict__ toRec,
                               const float* __restrict__ Wa,
                               float* __restrict__ ex_out, float* __restrict__ segsumP, int E)
{
    int e = blockIdx.x * blockDim.x + threadIdx.x;
    if (e >= E) return;
    int fi = __builtin_nontemporal_load(inc + e);
    int ti = __builtin_nontemporal_load(inc + E + e);
    float4 fbuf[2], tbuf[2];
    const float4* fp4 = (const float4*)(fromRec + (size_t)fi * RSTRIDE);
    const float4* tp4 = (const float4*)(toRec + (size_t)ti * RSTRIDE);
    fbuf[0] = fp4[0]; fbuf[1] = fp4[1];
    tbuf[0] = tp4[0]; tbuf[1] = tp4[1];
    const __half* fh = (const __half*)fbuf;
    const __half* th = (const __half*)tbuf;
    float fr[16], tr[16];
#pragma unroll
    for (int j = 0; j < 16; ++j) fr[j] = __half2float(fh[j]);
#pragma unroll
    for (int j = 0; j < 16; ++j) tr[j] = __half2float(th[j]);
    float raw = fr[15] + tr[15];
#pragma unroll
    for (int j = 0; j < 3; ++j) {
        float fd = tr[12] * fr[j] + tr[13] * fr[3 + j] + tr[14] * fr[6 + j] - fr[9 + j];
        float td = fr[12] * tr[j] + fr[13] * tr[3 + j] + fr[14] * tr[6 + j] - tr[9 + j];
        raw += silu_f(fd) * Wa[9 + j] + silu_f(td) * Wa[21 + j];
    }
    float ex = __expf(raw);
    __builtin_nontemporal_store(ex, ex_out + e);
    size_t slot = ((size_t)fi * NREP + (threadIdx.x & (NREP - 1))) * SEG_PAD;
    atomicAdd(&segsumP[slot], ex);
}

__global__ void seg_reduce(const float* __restrict__ segsumP, float* __restrict__ segsum, int NF)
{
    int k = blockIdx.x * blockDim.x + threadIdx.x;
    if (k >= NF) return;
    float s = 0.f;
#pragma unroll
    for (int r = 0; r < NREP; ++r) s += segsumP[((size_t)k * NREP + r) * SEG_PAD];
    segsum[k] = s;
}

extern "C" void kernel_launch(void* const* d_in, const int* in_sizes, int n_in,
                              void* d_out, int out_size, void* d_ws, size_t ws_size,
                              hipStream_t stream)
{
    const float* from_vec   = (const float*)d_in[0];
    const float* to_vec     = (const float*)d_in[1];
    const float* from_frame = (const float*)d_in[2];
    const float* to_frame   = (const float*)d_in[3];
    const float* from_pos   = (const float*)d_in[4];
    const float* to_pos     = (const float*)d_in[5];
    const float* W_from     = (const float*)d_in[6];
    const float* W_to       = (const float*)d_in[7];
    const float* W_attn     = (const float*)d_in[8];
    const int*   inc        = (const int*)d_in[9];

    const int NF = in_sizes[0] / 48;   // 50000
    const int NT = in_sizes[1] / 48;   // 100000
    const int E  = in_sizes[9] / 2;    // 1600000

    float* out = (float*)d_out;
    unsigned char* ws = (unsigned char*)d_ws;

    const int nbins = (NF + KPB - 1) >> KPB_SHIFT;        // 25
    const int nblk  = (E + EPB - 1) / EPB;                // 3125
    const int nPreF = (NF + 255) / 256;
    const int nPreT = (NT + 255) / 256;

    auto align256 = [](size_t x) { return (x + 255) & ~(size_t)255; };

    size_t offFrom = 0;                                              // partial overlays recs
    size_t offTo   = align256(offFrom + (size_t)NF * RSTRIDE * 2);   // fp16
    size_t recEnd  = offTo + (size_t)NT * RSTRIDE * 2;
    size_t offPair = align256(recEnd);
    size_t offBO   = align256(offPair + (size_t)nblk * EPB * 4);
    size_t offSeg  = align256(offBO + (size_t)nblk * (nbins + 1) * 4);
    size_t needFull = offSeg + (size_t)NF * 4;

    const size_t partialSz = (size_t)nbins * SLICES * KPB * 4;       // 4.71MB, overlays recs (4.8MB)
    const size_t recsz   = ((size_t)NF + NT) * RSTRIDE * 2;
    const size_t padsz   = (size_t)NF * NREP * SEG_PAD * 4;
    const size_t needPad = recsz + padsz + (size_t)NF * 4 + 512;

    const int B = 256;
    const int span = (nblk + SLICES - 1) / SLICES;
    if (ws_size >= needFull && nbins <= MAXBINS && partialSz <= recsz && span <= GSPAN) {
        __half*   fromRec  = (__half*)(ws + offFrom);
        __half*   toRec    = (__half*)(ws + offTo);
        unsigned* pairs    = (unsigned*)(ws + offPair);
        unsigned* binoff   = (unsigned*)(ws + offBO);
        float*    segsum   = (float*)(ws + offSeg);
        float*    partial  = (float*)(ws + offFrom);   // overlays recs (dead after fused)

        setup_kernel<<<nPreF + nPreT, B, 0, stream>>>(
            from_vec, from_frame, from_pos, W_from,
            to_vec, to_frame, to_pos, W_to, W_attn,
            fromRec, toRec, NF, NT, nPreF);
        edge_score_fused<<<nblk, B, 0, stream>>>(inc, fromRec, toRec, W_attn, binoff,
                                                 out, pairs, E, nbins, nblk);
        binsum_part<<<nbins * SLICES, 512, 0, stream>>>(pairs, binoff, partial, nbins, nblk);
        binsum_reduce<<<(NF + B - 1) / B, B, 0, stream>>>(partial, segsum, NF);
        edge_norm4<<<(E / 4 + B - 1) / B, B, 0, stream>>>(inc, segsum, out, E);
    } else if (ws_size >= needPad) {
        __half* fromRec = (__half*)ws;
        __half* toRec   = fromRec + (size_t)NF * RSTRIDE;
        float* segsumP  = (float*)(ws + align256(recsz));
        float* segsum   = segsumP + (size_t)NF * NREP * SEG_PAD;
        hipMemsetAsync(segsumP, 0, padsz, stream);
        pre_node_k<<<nPreF, B, 0, stream>>>(from_vec, from_frame, from_pos, W_from, W_attn, 0,  fromRec, NF);
        pre_node_k<<<nPreT, B, 0, stream>>>(to_vec, to_frame, to_pos, W_to, W_attn, 12, toRec, NT);
        edge_score_pad<<<(E + B - 1) / B, B, 0, stream>>>(inc, fromRec, toRec, W_attn, out, segsumP, E);
        seg_reduce<<<(NF + B - 1) / B, B, 0, stream>>>(segsumP, segsum, NF);
        edge_norm4<<<(E / 4 + B - 1) / B, B, 0, stream>>>(inc, segsum, out, E);
    }
}